// Round 7
// baseline (214.392 us; speedup 1.0000x reference)
//
#include <hip/hip_runtime.h>
#include <hip/hip_bf16.h>
#include <math.h>

#define N_ENT   100000
#define DIM     128
#define N_EDGES 1600000
#define BATCH   8192
#define EPS     1e-5f
#define CAP     128          // max neighbors stored per needed node (Poisson(16) tail ~0)
#define NSTAT_BLK 512

// ---------------- ws layout (4-byte elements) ----------------
#define WS_SCALE     256        // f[128]
#define WS_SHIFT     384        // f[128]
#define WS_COUNT     512        // i[16] (count in [0])
#define WS_BCOUNT    528        // i[8192] per-slot edge count (== degree)
#define WS_SLOTOF    8720       // i[100000]  (-1 = unneeded, -2 = marked, >=0 = slot)
#define WS_BUCKET    108720     // i[8192*128]   (16B aligned)
#define WS_SLOTHEAD  1157296    // f[8192*32]    per-slot head logits (age 0-6, occ 7-27, gender 28)
#define WS_PARTIAL   1419440    // f[512*256]    stats partials

// K0: init all state the pipeline needs (ws is poisoned 0xAA before every launch).
__global__ __launch_bounds__(256) void init_kernel(int* __restrict__ slot_of,
                                                   int* __restrict__ bcount,
                                                   int* __restrict__ count,
                                                   float* __restrict__ out_loss) {
    int n = blockIdx.x * 256 + threadIdx.x;
    if (n < N_ENT) slot_of[n] = -1;
    if (n < BATCH) bcount[n] = 0;
    if (n < 16)    count[n] = 0;
    if (n == 0)    out_loss[0] = 0.f;
}

// K1: per-column sum/sumsq of E, float4 lanes, x4-unrolled rows, NO atomics.
__global__ __launch_bounds__(256) void stats_kernel(const float4* __restrict__ E4,
                                                    float* __restrict__ partial) {
    int t = threadIdx.x;
    int cg = t & 31;
    int rs = t >> 5;
    const int STRIDE = NSTAT_BLK * 8;   // 4096 rows per sweep
    float sx = 0.f, sy = 0.f, sz = 0.f, sw = 0.f;
    float qx = 0.f, qy = 0.f, qz = 0.f, qw = 0.f;
    const float4 z4 = make_float4(0.f, 0.f, 0.f, 0.f);
    for (int r = blockIdx.x * 8 + rs; r < N_ENT; r += 4 * STRIDE) {
        int r1 = r + STRIDE, r2 = r + 2 * STRIDE, r3 = r + 3 * STRIDE;
        float4 v0 = E4[(size_t)r * 32 + cg];
        float4 v1 = (r1 < N_ENT) ? E4[(size_t)r1 * 32 + cg] : z4;
        float4 v2 = (r2 < N_ENT) ? E4[(size_t)r2 * 32 + cg] : z4;
        float4 v3 = (r3 < N_ENT) ? E4[(size_t)r3 * 32 + cg] : z4;
        sx += v0.x + v1.x + v2.x + v3.x;
        sy += v0.y + v1.y + v2.y + v3.y;
        sz += v0.z + v1.z + v2.z + v3.z;
        sw += v0.w + v1.w + v2.w + v3.w;
        qx += v0.x * v0.x + v1.x * v1.x + v2.x * v2.x + v3.x * v3.x;
        qy += v0.y * v0.y + v1.y * v1.y + v2.y * v2.y + v3.y * v3.y;
        qz += v0.z * v0.z + v1.z * v1.z + v2.z * v2.z + v3.z * v3.z;
        qw += v0.w * v0.w + v1.w * v1.w + v2.w * v2.w + v3.w * v3.w;
    }
    __shared__ float sh[8 * 256];
    sh[0 * 256 + t] = sx; sh[1 * 256 + t] = sy;
    sh[2 * 256 + t] = sz; sh[3 * 256 + t] = sw;
    sh[4 * 256 + t] = qx; sh[5 * 256 + t] = qy;
    sh[6 * 256 + t] = qz; sh[7 * 256 + t] = qw;
    __syncthreads();
    for (int o = 128; o >= 32; o >>= 1) {
        if (t < o) {
#pragma unroll
            for (int j = 0; j < 8; ++j) sh[j * 256 + t] += sh[j * 256 + t + o];
        }
        __syncthreads();
    }
    if (t < 32) {
#pragma unroll
        for (int j = 0; j < 8; ++j)
            partial[blockIdx.x * 256 + j * 32 + t] = sh[j * 256 + t];
    }
}

// K2: reduce partials; fold batchnorm into per-column scale/shift.
__global__ __launch_bounds__(256) void finalize_kernel(const float* __restrict__ partial,
                                                       const float* __restrict__ gamma,
                                                       const float* __restrict__ beta,
                                                       float* __restrict__ scale,
                                                       float* __restrict__ shift) {
    int t = threadIdx.x;
    float s = 0.f;
    for (int b = 0; b < NSTAT_BLK; ++b) s += partial[b * 256 + t];
    __shared__ float tot[256];
    tot[t] = s;
    __syncthreads();
    if (t < 128) {
        int ti = t >> 2, j = t & 3;
        const float invn = 1.0f / (float)N_ENT;
        float mu = tot[j * 32 + ti] * invn;
        float var = tot[(j + 4) * 32 + ti] * invn - mu * mu;
        float rs = rsqrtf(var + EPS);
        float sc = gamma[t] * rs;
        scale[t] = sc;
        shift[t] = beta[t] - mu * sc;
    }
}

// K3: mark needed nodes (idempotent stores; slot_of pre-filled with -1).
__global__ __launch_bounds__(256) void mark_kernel(const int* __restrict__ neighbor,
                                                   int* __restrict__ slot_of) {
    int b = blockIdx.x * 256 + threadIdx.x;
    if (b < BATCH) slot_of[neighbor[b]] = -2;
}

// K4: assign compact slots to marked nodes — 1 global atomic per block.
__global__ __launch_bounds__(256) void compact_kernel(int* __restrict__ slot_of,
                                                      int* __restrict__ count) {
    int n = blockIdx.x * 256 + threadIdx.x;
    bool marked = (n < N_ENT && slot_of[n] == -2);
    unsigned long long m = __ballot(marked);
    int lane = threadIdx.x & 63;
    int wid = threadIdx.x >> 6;
    int prefix = __popcll(m & ((1ull << lane) - 1ull));
    __shared__ int wsum[4];
    __shared__ int base;
    if (lane == 0) wsum[wid] = __popcll(m);
    __syncthreads();
    if (threadIdx.x == 0) {
        base = atomicAdd(count, wsum[0] + wsum[1] + wsum[2] + wsum[3]);
    }
    __syncthreads();
    int wbase = 0;
    for (int i = 0; i < wid; ++i) wbase += wsum[i];
    if (marked) slot_of[n] = base + wbase + prefix;
}

// K5: single-pass edge bucket — each thread owns 2 int4s (8 edges), so up to
// 8 independent slot_of probes are in flight (latency-bound kernel -> MLP).
__global__ __launch_bounds__(256) void edge_bucket_kernel(const int4* __restrict__ src4,
                                                          const int4* __restrict__ dst4,
                                                          const int* __restrict__ slot_of,
                                                          int* __restrict__ bcount,
                                                          int* __restrict__ bucket) {
    const int n4 = N_EDGES / 4;   // 400000, exact
    int tid = blockIdx.x * blockDim.x + threadIdx.x;
    int e0 = tid * 2;
    int e1 = tid * 2 + 1;
    if (e0 >= n4) return;
    int4 d0 = dst4[e0];
    int4 s0 = src4[e0];
    bool has1 = (e1 < n4);
    int4 d1 = has1 ? dst4[e1] : make_int4(0, 0, 0, 0);
    int4 s1 = has1 ? src4[e1] : make_int4(0, 0, 0, 0);
    int sl0 = slot_of[d0.x];
    int sl1 = slot_of[d0.y];
    int sl2 = slot_of[d0.z];
    int sl3 = slot_of[d0.w];
    int sl4 = has1 ? slot_of[d1.x] : -1;
    int sl5 = has1 ? slot_of[d1.y] : -1;
    int sl6 = has1 ? slot_of[d1.z] : -1;
    int sl7 = has1 ? slot_of[d1.w] : -1;
    if (sl0 >= 0) { int p = atomicAdd(&bcount[sl0], 1); if (p < CAP) bucket[sl0 * CAP + p] = s0.x; }
    if (sl1 >= 0) { int p = atomicAdd(&bcount[sl1], 1); if (p < CAP) bucket[sl1 * CAP + p] = s0.y; }
    if (sl2 >= 0) { int p = atomicAdd(&bcount[sl2], 1); if (p < CAP) bucket[sl2 * CAP + p] = s0.z; }
    if (sl3 >= 0) { int p = atomicAdd(&bcount[sl3], 1); if (p < CAP) bucket[sl3 * CAP + p] = s0.w; }
    if (sl4 >= 0) { int p = atomicAdd(&bcount[sl4], 1); if (p < CAP) bucket[sl4 * CAP + p] = s1.x; }
    if (sl5 >= 0) { int p = atomicAdd(&bcount[sl5], 1); if (p < CAP) bucket[sl5 * CAP + p] = s1.y; }
    if (sl6 >= 0) { int p = atomicAdd(&bcount[sl6], 1); if (p < CAP) bucket[sl6 * CAP + p] = s1.z; }
    if (sl7 >= 0) { int p = atomicAdd(&bcount[sl7], 1); if (p < CAP) bucket[sl7 * CAP + p] = s1.w; }
}

// K6: FUSED per-slot pipeline. One 64-lane wave per slot:
//  (a) gather-sum neighbor E rows — 4 rows per half-wave in flight (8/wave)
//  (b) normalize -> h row in wave-local LDS
//  (c) 1x128 @ 128x128 GEMM + bias + relu -> h2 back into LDS
//  (d) 29 head logits (age7/occ21/gender1) -> slot_heads
// No early return (guarded by pred) so __syncthreads is uniform.
__global__ __launch_bounds__(256) void gather_gemm_heads_kernel(
        const float4* __restrict__ E4,
        const int* __restrict__ count,
        const int* __restrict__ bcount,
        const int* __restrict__ bucket,
        const float4* __restrict__ scale4,
        const float4* __restrict__ shift4,
        const float4* __restrict__ W4,
        const float4* __restrict__ bias4,
        const float* __restrict__ W_g,
        const float* __restrict__ b_g,
        const float* __restrict__ W_age,
        const float* __restrict__ b_age,
        const float* __restrict__ W_occ,
        const float* __restrict__ b_occ,
        float* __restrict__ slot_heads) {
    __shared__ float hrow[4][128];
    int t = threadIdx.x;
    int wv = t >> 6;
    int slot = blockIdx.x * 4 + wv;
    int U = count[0];
    bool pred = (slot < U);
    int lane = t & 63;
    int q = lane & 31;
    int sub = lane >> 5;
    int dg = pred ? bcount[slot] : 0;
    int m = dg < CAP ? dg : CAP;
    const int* bk = bucket + slot * CAP;

    // (a) gather: half-wave `sub` covers rows {sub, sub+2, ...}; 4-deep unroll
    //     -> 8 rows (4 KB) in flight per wave; MLP hides ~900-cyc HBM misses.
    float ax = 0.f, ay = 0.f, az = 0.f, aw = 0.f;
    int i = sub;
    for (; i + 6 < m; i += 8) {
        int r0 = bk[i], r1 = bk[i + 2], r2 = bk[i + 4], r3 = bk[i + 6];
        float4 v0 = E4[(size_t)r0 * 32 + q];
        float4 v1 = E4[(size_t)r1 * 32 + q];
        float4 v2 = E4[(size_t)r2 * 32 + q];
        float4 v3 = E4[(size_t)r3 * 32 + q];
        ax += v0.x + v1.x + v2.x + v3.x;
        ay += v0.y + v1.y + v2.y + v3.y;
        az += v0.z + v1.z + v2.z + v3.z;
        aw += v0.w + v1.w + v2.w + v3.w;
    }
    for (; i < m; i += 2) {
        int r0 = bk[i];
        float4 v0 = E4[(size_t)r0 * 32 + q];
        ax += v0.x; ay += v0.y; az += v0.z; aw += v0.w;
    }
    ax += __shfl_down(ax, 32);
    ay += __shfl_down(ay, 32);
    az += __shfl_down(az, 32);
    aw += __shfl_down(aw, 32);
    // (b) normalize + stage to LDS
    if (sub == 0) {
        float fdg = (float)dg;
        float rd = 1.0f / fmaxf(fdg, 1.0f);
        float4 sc = scale4[q];
        float4 sf = shift4[q];
        float4 o;
        o.x = (ax * sc.x + fdg * sf.x) * rd;
        o.y = (ay * sc.y + fdg * sf.y) * rd;
        o.z = (az * sc.z + fdg * sf.z) * rd;
        o.w = (aw * sc.w + fdg * sf.w) * rd;
        ((float4*)hrow[wv])[q] = o;
    }
    __syncthreads();
    // (c) GEMM: lane computes cols [4q,4q+4) over k in [64*sub, 64*sub+64)
    float cx = 0.f, cy = 0.f, cz = 0.f, cw = 0.f;
    int k0 = sub * 64;
#pragma unroll 4
    for (int kk = 0; kk < 64; ++kk) {
        float a = hrow[wv][k0 + kk];
        float4 w = W4[(size_t)(k0 + kk) * 32 + q];
        cx += a * w.x; cy += a * w.y; cz += a * w.z; cw += a * w.w;
    }
    cx += __shfl_down(cx, 32);
    cy += __shfl_down(cy, 32);
    cz += __shfl_down(cz, 32);
    cw += __shfl_down(cw, 32);
    __syncthreads();   // all hrow reads done before overwrite
    if (sub == 0) {
        float4 bv = bias4[q];
        float4 h2;
        h2.x = fmaxf(cx + bv.x, 0.f);
        h2.y = fmaxf(cy + bv.y, 0.f);
        h2.z = fmaxf(cz + bv.z, 0.f);
        h2.w = fmaxf(cw + bv.w, 0.f);
        ((float4*)hrow[wv])[q] = h2;
    }
    __syncthreads();
    // (d) heads: 29 lanes, one logit each; uniform loop, per-lane weight ptr
    if (pred && lane < 29) {
        const float* Wp;
        int stride;
        float acch;
        if (lane < 7)       { Wp = W_age + lane;      stride = 7;  acch = b_age[lane]; }
        else if (lane < 28) { Wp = W_occ + (lane - 7); stride = 21; acch = b_occ[lane - 7]; }
        else                { Wp = W_g;               stride = 1;  acch = b_g[0]; }
#pragma unroll 4
        for (int d = 0; d < DIM; ++d) acch += hrow[wv][d] * Wp[d * stride];
        slot_heads[slot * 32 + lane] = acch;
    }
}

// K7: map per-slot head logits to batch outputs + fused BCE loss.
__global__ __launch_bounds__(256) void map_loss_kernel(const float* __restrict__ slot_heads,
                                                       const int* __restrict__ slot_of,
                                                       const int* __restrict__ neighbor,
                                                       const int* __restrict__ gender,
                                                       float* __restrict__ out_age,
                                                       float* __restrict__ out_gender,
                                                       float* __restrict__ out_occ,
                                                       float* __restrict__ out_loss) {
    int b = blockIdx.x * 256 + threadIdx.x;
    float val = 0.f;
    if (b < BATCH) {
        int slot = slot_of[neighbor[b]];
        const float* hs = slot_heads + (size_t)slot * 32;
#pragma unroll
        for (int c = 0; c < 7; ++c)  out_age[b * 7 + c] = hs[c];
#pragma unroll
        for (int c = 0; c < 21; ++c) out_occ[b * 21 + c] = hs[7 + c];
        float x = hs[28];
        out_gender[b] = x;
        float z = (float)gender[b];
        val = fmaxf(x, 0.f) - x * z + log1pf(expf(-fabsf(x)));
    }
    __shared__ float sh[256];
    sh[threadIdx.x] = val;
    __syncthreads();
    for (int o = 128; o > 0; o >>= 1) {
        if (threadIdx.x < o) sh[threadIdx.x] += sh[threadIdx.x + o];
        __syncthreads();
    }
    if (threadIdx.x == 0) atomicAdd(out_loss, sh[0] * (1.0f / (float)BATCH));
}

extern "C" void kernel_launch(void* const* d_in, const int* in_sizes, int n_in,
                              void* d_out, int out_size, void* d_ws, size_t ws_size,
                              hipStream_t stream) {
    const float* E      = (const float*)d_in[0];
    const float* gamma  = (const float*)d_in[1];
    const float* beta   = (const float*)d_in[2];
    const float* W_gnn  = (const float*)d_in[3];
    const float* b_gnn  = (const float*)d_in[4];
    const float* W_g    = (const float*)d_in[5];
    const float* b_g    = (const float*)d_in[6];
    const float* W_age  = (const float*)d_in[7];
    const float* b_age  = (const float*)d_in[8];
    const float* W_occ  = (const float*)d_in[9];
    const float* b_occ  = (const float*)d_in[10];
    const int*   src    = (const int*)d_in[11];
    const int*   dst    = (const int*)d_in[12];
    const int*   neigh  = (const int*)d_in[13];
    const int*   gender = (const int*)d_in[14];

    float* ws        = (float*)d_ws;
    int*   wsi       = (int*)d_ws;
    float* scale     = ws + WS_SCALE;
    float* shift     = ws + WS_SHIFT;
    int*   count     = wsi + WS_COUNT;
    int*   bcount    = wsi + WS_BCOUNT;
    int*   slot_of   = wsi + WS_SLOTOF;
    int*   bucket    = wsi + WS_BUCKET;
    float* slot_hd   = ws + WS_SLOTHEAD;
    float* partial   = ws + WS_PARTIAL;

    float* out       = (float*)d_out;
    float* out_loss  = out;                         // [1]
    float* out_age   = out + 1;                     // [8192,7]
    float* out_gen   = out + 1 + BATCH * 7;         // [8192]
    float* out_occ   = out + 1 + BATCH * 7 + BATCH; // [8192,21]

    init_kernel<<<(N_ENT + 255) / 256, 256, 0, stream>>>(slot_of, bcount, count, out_loss);
    stats_kernel<<<NSTAT_BLK, 256, 0, stream>>>((const float4*)E, partial);
    finalize_kernel<<<1, 256, 0, stream>>>(partial, gamma, beta, scale, shift);
    mark_kernel<<<BATCH / 256, 256, 0, stream>>>(neigh, slot_of);
    compact_kernel<<<(N_ENT + 255) / 256, 256, 0, stream>>>(slot_of, count);
    {
        const int n4 = N_EDGES / 4;
        int nthreads = (n4 + 1) / 2;
        edge_bucket_kernel<<<(nthreads + 255) / 256, 256, 0, stream>>>(
            (const int4*)src, (const int4*)dst, slot_of, bcount, bucket);
    }
    gather_gemm_heads_kernel<<<BATCH / 4, 256, 0, stream>>>(
        (const float4*)E, count, bcount, bucket,
        (const float4*)scale, (const float4*)shift,
        (const float4*)W_gnn, (const float4*)b_gnn,
        W_g, b_g, W_age, b_age, W_occ, b_occ, slot_hd);
    map_loss_kernel<<<BATCH / 256, 256, 0, stream>>>(slot_hd, slot_of, neigh, gender,
                                                     out_age, out_gen, out_occ, out_loss);
}

// Round 8
// 213.498 us; speedup vs baseline: 1.0042x; 1.0042x over previous
//
#include <hip/hip_runtime.h>
#include <hip/hip_bf16.h>
#include <math.h>

#define N_ENT   100000
#define DIM     128
#define N_EDGES 1600000
#define BATCH   8192
#define EPS     1e-5f
#define CAP     128          // max neighbors stored per needed node (Poisson(16) tail ~0)
#define NSTAT_BLK 512

// ---------------- ws layout (4-byte elements) ----------------
#define WS_SCALE     256        // f[128]
#define WS_SHIFT     384        // f[128]
#define WS_COUNT     512        // i[16] (count in [0])
#define WS_BCOUNT    528        // i[8192] per-slot edge count (== degree)
#define WS_SLOTOF    8720       // i[100000]  (-1 = unneeded, -2 = marked, >=0 = slot)
#define WS_BUCKET    108720     // i[8192*128]   (16B aligned)
#define WS_SLOTHEAD  1157296    // f[8192*32]    per-slot head logits (age 0-6, occ 7-27, gender 28)
#define WS_PARTIAL   1419440    // f[512*256]    stats partials
#define WS_EBF       1550512    // bf16[100000*128] as ushort (25.6 MB), 16B aligned

// round-to-nearest-even fp32 -> bf16 (finite inputs)
__device__ __forceinline__ unsigned short f2bf(float f) {
    union { float f; unsigned u; } v; v.f = f;
    unsigned r = v.u + 0x7FFFu + ((v.u >> 16) & 1u);
    return (unsigned short)(r >> 16);
}
__device__ __forceinline__ float bf2f(unsigned short b) {
    union { unsigned u; float f; } v; v.u = ((unsigned)b) << 16;
    return v.f;
}

// K0: init all state the pipeline needs (ws is poisoned 0xAA before every launch).
__global__ __launch_bounds__(256) void init_kernel(int* __restrict__ slot_of,
                                                   int* __restrict__ bcount,
                                                   int* __restrict__ count,
                                                   float* __restrict__ out_loss) {
    int n = blockIdx.x * 256 + threadIdx.x;
    if (n < N_ENT) slot_of[n] = -1;
    if (n < BATCH) bcount[n] = 0;
    if (n < 16)    count[n] = 0;
    if (n == 0)    out_loss[0] = 0.f;
}

// K1: per-column sum/sumsq of E (fp32, exact) + side-write bf16 copy of E.
// The bf16 copy is written immediately before gather uses it -> L2/LLC warm.
__global__ __launch_bounds__(256) void stats_kernel(const float4* __restrict__ E4,
                                                    unsigned short* __restrict__ Ebf,
                                                    float* __restrict__ partial) {
    int t = threadIdx.x;
    int cg = t & 31;
    int rs = t >> 5;
    const int STRIDE = NSTAT_BLK * 8;   // 4096 rows per sweep
    float sx = 0.f, sy = 0.f, sz = 0.f, sw = 0.f;
    float qx = 0.f, qy = 0.f, qz = 0.f, qw = 0.f;
    const float4 z4 = make_float4(0.f, 0.f, 0.f, 0.f);
    for (int r = blockIdx.x * 8 + rs; r < N_ENT; r += 4 * STRIDE) {
        int r1 = r + STRIDE, r2 = r + 2 * STRIDE, r3 = r + 3 * STRIDE;
        float4 v0 = E4[(size_t)r * 32 + cg];
        float4 v1 = (r1 < N_ENT) ? E4[(size_t)r1 * 32 + cg] : z4;
        float4 v2 = (r2 < N_ENT) ? E4[(size_t)r2 * 32 + cg] : z4;
        float4 v3 = (r3 < N_ENT) ? E4[(size_t)r3 * 32 + cg] : z4;
        // bf16 side-copy (RNE), ushort4 = 8 B/lane, coalesced
        {
            ushort4 o;
            o.x = f2bf(v0.x); o.y = f2bf(v0.y); o.z = f2bf(v0.z); o.w = f2bf(v0.w);
            ((ushort4*)(Ebf + ((size_t)r << 7)))[cg] = o;
            if (r1 < N_ENT) {
                ushort4 o1; o1.x = f2bf(v1.x); o1.y = f2bf(v1.y); o1.z = f2bf(v1.z); o1.w = f2bf(v1.w);
                ((ushort4*)(Ebf + ((size_t)r1 << 7)))[cg] = o1;
            }
            if (r2 < N_ENT) {
                ushort4 o2; o2.x = f2bf(v2.x); o2.y = f2bf(v2.y); o2.z = f2bf(v2.z); o2.w = f2bf(v2.w);
                ((ushort4*)(Ebf + ((size_t)r2 << 7)))[cg] = o2;
            }
            if (r3 < N_ENT) {
                ushort4 o3; o3.x = f2bf(v3.x); o3.y = f2bf(v3.y); o3.z = f2bf(v3.z); o3.w = f2bf(v3.w);
                ((ushort4*)(Ebf + ((size_t)r3 << 7)))[cg] = o3;
            }
        }
        sx += v0.x + v1.x + v2.x + v3.x;
        sy += v0.y + v1.y + v2.y + v3.y;
        sz += v0.z + v1.z + v2.z + v3.z;
        sw += v0.w + v1.w + v2.w + v3.w;
        qx += v0.x * v0.x + v1.x * v1.x + v2.x * v2.x + v3.x * v3.x;
        qy += v0.y * v0.y + v1.y * v1.y + v2.y * v2.y + v3.y * v3.y;
        qz += v0.z * v0.z + v1.z * v1.z + v2.z * v2.z + v3.z * v3.z;
        qw += v0.w * v0.w + v1.w * v1.w + v2.w * v2.w + v3.w * v3.w;
    }
    __shared__ float sh[8 * 256];
    sh[0 * 256 + t] = sx; sh[1 * 256 + t] = sy;
    sh[2 * 256 + t] = sz; sh[3 * 256 + t] = sw;
    sh[4 * 256 + t] = qx; sh[5 * 256 + t] = qy;
    sh[6 * 256 + t] = qz; sh[7 * 256 + t] = qw;
    __syncthreads();
    for (int o = 128; o >= 32; o >>= 1) {
        if (t < o) {
#pragma unroll
            for (int j = 0; j < 8; ++j) sh[j * 256 + t] += sh[j * 256 + t + o];
        }
        __syncthreads();
    }
    if (t < 32) {
#pragma unroll
        for (int j = 0; j < 8; ++j)
            partial[blockIdx.x * 256 + j * 32 + t] = sh[j * 256 + t];
    }
}

// K2: reduce partials; fold batchnorm into per-column scale/shift.
__global__ __launch_bounds__(256) void finalize_kernel(const float* __restrict__ partial,
                                                       const float* __restrict__ gamma,
                                                       const float* __restrict__ beta,
                                                       float* __restrict__ scale,
                                                       float* __restrict__ shift) {
    int t = threadIdx.x;
    float s = 0.f;
    for (int b = 0; b < NSTAT_BLK; ++b) s += partial[b * 256 + t];
    __shared__ float tot[256];
    tot[t] = s;
    __syncthreads();
    if (t < 128) {
        int ti = t >> 2, j = t & 3;
        const float invn = 1.0f / (float)N_ENT;
        float mu = tot[j * 32 + ti] * invn;
        float var = tot[(j + 4) * 32 + ti] * invn - mu * mu;
        float rs = rsqrtf(var + EPS);
        float sc = gamma[t] * rs;
        scale[t] = sc;
        shift[t] = beta[t] - mu * sc;
    }
}

// K3: mark needed nodes (idempotent stores; slot_of pre-filled with -1).
__global__ __launch_bounds__(256) void mark_kernel(const int* __restrict__ neighbor,
                                                   int* __restrict__ slot_of) {
    int b = blockIdx.x * 256 + threadIdx.x;
    if (b < BATCH) slot_of[neighbor[b]] = -2;
}

// K4: assign compact slots to marked nodes — 1 global atomic per block.
__global__ __launch_bounds__(256) void compact_kernel(int* __restrict__ slot_of,
                                                      int* __restrict__ count) {
    int n = blockIdx.x * 256 + threadIdx.x;
    bool marked = (n < N_ENT && slot_of[n] == -2);
    unsigned long long m = __ballot(marked);
    int lane = threadIdx.x & 63;
    int wid = threadIdx.x >> 6;
    int prefix = __popcll(m & ((1ull << lane) - 1ull));
    __shared__ int wsum[4];
    __shared__ int base;
    if (lane == 0) wsum[wid] = __popcll(m);
    __syncthreads();
    if (threadIdx.x == 0) {
        base = atomicAdd(count, wsum[0] + wsum[1] + wsum[2] + wsum[3]);
    }
    __syncthreads();
    int wbase = 0;
    for (int i = 0; i < wid; ++i) wbase += wsum[i];
    if (marked) slot_of[n] = base + wbase + prefix;
}

// K5: single-pass edge bucket — 8 edges/thread, 8 independent slot_of probes.
__global__ __launch_bounds__(256) void edge_bucket_kernel(const int4* __restrict__ src4,
                                                          const int4* __restrict__ dst4,
                                                          const int* __restrict__ slot_of,
                                                          int* __restrict__ bcount,
                                                          int* __restrict__ bucket) {
    const int n4 = N_EDGES / 4;   // 400000, exact
    int tid = blockIdx.x * blockDim.x + threadIdx.x;
    int e0 = tid * 2;
    int e1 = tid * 2 + 1;
    if (e0 >= n4) return;
    int4 d0 = dst4[e0];
    int4 s0 = src4[e0];
    bool has1 = (e1 < n4);
    int4 d1 = has1 ? dst4[e1] : make_int4(0, 0, 0, 0);
    int4 s1 = has1 ? src4[e1] : make_int4(0, 0, 0, 0);
    int sl0 = slot_of[d0.x];
    int sl1 = slot_of[d0.y];
    int sl2 = slot_of[d0.z];
    int sl3 = slot_of[d0.w];
    int sl4 = has1 ? slot_of[d1.x] : -1;
    int sl5 = has1 ? slot_of[d1.y] : -1;
    int sl6 = has1 ? slot_of[d1.z] : -1;
    int sl7 = has1 ? slot_of[d1.w] : -1;
    if (sl0 >= 0) { int p = atomicAdd(&bcount[sl0], 1); if (p < CAP) bucket[sl0 * CAP + p] = s0.x; }
    if (sl1 >= 0) { int p = atomicAdd(&bcount[sl1], 1); if (p < CAP) bucket[sl1 * CAP + p] = s0.y; }
    if (sl2 >= 0) { int p = atomicAdd(&bcount[sl2], 1); if (p < CAP) bucket[sl2 * CAP + p] = s0.z; }
    if (sl3 >= 0) { int p = atomicAdd(&bcount[sl3], 1); if (p < CAP) bucket[sl3 * CAP + p] = s0.w; }
    if (sl4 >= 0) { int p = atomicAdd(&bcount[sl4], 1); if (p < CAP) bucket[sl4 * CAP + p] = s1.x; }
    if (sl5 >= 0) { int p = atomicAdd(&bcount[sl5], 1); if (p < CAP) bucket[sl5 * CAP + p] = s1.y; }
    if (sl6 >= 0) { int p = atomicAdd(&bcount[sl6], 1); if (p < CAP) bucket[sl6 * CAP + p] = s1.z; }
    if (sl7 >= 0) { int p = atomicAdd(&bcount[sl7], 1); if (p < CAP) bucket[sl7 * CAP + p] = s1.w; }
}

// K6: FUSED per-slot pipeline. One 64-lane wave per slot:
//  (a) gather-sum neighbor rows from the bf16 E copy (256 B/row, L2/LLC-warm)
//  (b) normalize -> h row in wave-local LDS
//  (c) 1x128 @ 128x128 GEMM + bias + relu -> h2 back into LDS
//  (d) 29 head logits (age7/occ21/gender1) -> slot_heads
__global__ __launch_bounds__(256) void gather_gemm_heads_kernel(
        const unsigned short* __restrict__ Ebf,
        const int* __restrict__ count,
        const int* __restrict__ bcount,
        const int* __restrict__ bucket,
        const float4* __restrict__ scale4,
        const float4* __restrict__ shift4,
        const float4* __restrict__ W4,
        const float4* __restrict__ bias4,
        const float* __restrict__ W_g,
        const float* __restrict__ b_g,
        const float* __restrict__ W_age,
        const float* __restrict__ b_age,
        const float* __restrict__ W_occ,
        const float* __restrict__ b_occ,
        float* __restrict__ slot_heads) {
    __shared__ float hrow[4][128];
    int t = threadIdx.x;
    int wv = t >> 6;
    int slot = blockIdx.x * 4 + wv;
    int U = count[0];
    bool pred = (slot < U);
    int lane = t & 63;
    int q = lane & 31;
    int sub = lane >> 5;
    int dg = pred ? bcount[slot] : 0;
    int m = dg < CAP ? dg : CAP;
    const int* bk = bucket + slot * CAP;

    // (a) gather from bf16 copy: half-wave `sub` covers rows {sub, sub+2, ...};
    // 4-deep unroll -> 8 rows (2 KB) in flight per wave. Lane reads ushort4
    // (8 B) = cols [4q, 4q+4): same column mapping as the fp32 version.
    float ax = 0.f, ay = 0.f, az = 0.f, aw = 0.f;
    int i = sub;
    for (; i + 6 < m; i += 8) {
        int r0 = bk[i], r1 = bk[i + 2], r2 = bk[i + 4], r3 = bk[i + 6];
        ushort4 u0 = ((const ushort4*)(Ebf + ((size_t)r0 << 7)))[q];
        ushort4 u1 = ((const ushort4*)(Ebf + ((size_t)r1 << 7)))[q];
        ushort4 u2 = ((const ushort4*)(Ebf + ((size_t)r2 << 7)))[q];
        ushort4 u3 = ((const ushort4*)(Ebf + ((size_t)r3 << 7)))[q];
        ax += bf2f(u0.x) + bf2f(u1.x) + bf2f(u2.x) + bf2f(u3.x);
        ay += bf2f(u0.y) + bf2f(u1.y) + bf2f(u2.y) + bf2f(u3.y);
        az += bf2f(u0.z) + bf2f(u1.z) + bf2f(u2.z) + bf2f(u3.z);
        aw += bf2f(u0.w) + bf2f(u1.w) + bf2f(u2.w) + bf2f(u3.w);
    }
    for (; i < m; i += 2) {
        int r0 = bk[i];
        ushort4 u0 = ((const ushort4*)(Ebf + ((size_t)r0 << 7)))[q];
        ax += bf2f(u0.x); ay += bf2f(u0.y); az += bf2f(u0.z); aw += bf2f(u0.w);
    }
    ax += __shfl_down(ax, 32);
    ay += __shfl_down(ay, 32);
    az += __shfl_down(az, 32);
    aw += __shfl_down(aw, 32);
    // (b) normalize + stage to LDS
    if (sub == 0) {
        float fdg = (float)dg;
        float rd = 1.0f / fmaxf(fdg, 1.0f);
        float4 sc = scale4[q];
        float4 sf = shift4[q];
        float4 o;
        o.x = (ax * sc.x + fdg * sf.x) * rd;
        o.y = (ay * sc.y + fdg * sf.y) * rd;
        o.z = (az * sc.z + fdg * sf.z) * rd;
        o.w = (aw * sc.w + fdg * sf.w) * rd;
        ((float4*)hrow[wv])[q] = o;
    }
    __syncthreads();
    // (c) GEMM: lane computes cols [4q,4q+4) over k in [64*sub, 64*sub+64)
    float cx = 0.f, cy = 0.f, cz = 0.f, cw = 0.f;
    int k0 = sub * 64;
#pragma unroll 4
    for (int kk = 0; kk < 64; ++kk) {
        float a = hrow[wv][k0 + kk];
        float4 w = W4[(size_t)(k0 + kk) * 32 + q];
        cx += a * w.x; cy += a * w.y; cz += a * w.z; cw += a * w.w;
    }
    cx += __shfl_down(cx, 32);
    cy += __shfl_down(cy, 32);
    cz += __shfl_down(cz, 32);
    cw += __shfl_down(cw, 32);
    __syncthreads();   // all hrow reads done before overwrite
    if (sub == 0) {
        float4 bv = bias4[q];
        float4 h2;
        h2.x = fmaxf(cx + bv.x, 0.f);
        h2.y = fmaxf(cy + bv.y, 0.f);
        h2.z = fmaxf(cz + bv.z, 0.f);
        h2.w = fmaxf(cw + bv.w, 0.f);
        ((float4*)hrow[wv])[q] = h2;
    }
    __syncthreads();
    // (d) heads: 29 lanes, one logit each
    if (pred && lane < 29) {
        const float* Wp;
        int stride;
        float acch;
        if (lane < 7)       { Wp = W_age + lane;      stride = 7;  acch = b_age[lane]; }
        else if (lane < 28) { Wp = W_occ + (lane - 7); stride = 21; acch = b_occ[lane - 7]; }
        else                { Wp = W_g;               stride = 1;  acch = b_g[0]; }
#pragma unroll 4
        for (int d = 0; d < DIM; ++d) acch += hrow[wv][d] * Wp[d * stride];
        slot_heads[slot * 32 + lane] = acch;
    }
}

// K7: map per-slot head logits to batch outputs + fused BCE loss.
__global__ __launch_bounds__(256) void map_loss_kernel(const float* __restrict__ slot_heads,
                                                       const int* __restrict__ slot_of,
                                                       const int* __restrict__ neighbor,
                                                       const int* __restrict__ gender,
                                                       float* __restrict__ out_age,
                                                       float* __restrict__ out_gender,
                                                       float* __restrict__ out_occ,
                                                       float* __restrict__ out_loss) {
    int b = blockIdx.x * 256 + threadIdx.x;
    float val = 0.f;
    if (b < BATCH) {
        int slot = slot_of[neighbor[b]];
        const float* hs = slot_heads + (size_t)slot * 32;
#pragma unroll
        for (int c = 0; c < 7; ++c)  out_age[b * 7 + c] = hs[c];
#pragma unroll
        for (int c = 0; c < 21; ++c) out_occ[b * 21 + c] = hs[7 + c];
        float x = hs[28];
        out_gender[b] = x;
        float z = (float)gender[b];
        val = fmaxf(x, 0.f) - x * z + log1pf(expf(-fabsf(x)));
    }
    __shared__ float sh[256];
    sh[threadIdx.x] = val;
    __syncthreads();
    for (int o = 128; o > 0; o >>= 1) {
        if (threadIdx.x < o) sh[threadIdx.x] += sh[threadIdx.x + o];
        __syncthreads();
    }
    if (threadIdx.x == 0) atomicAdd(out_loss, sh[0] * (1.0f / (float)BATCH));
}

extern "C" void kernel_launch(void* const* d_in, const int* in_sizes, int n_in,
                              void* d_out, int out_size, void* d_ws, size_t ws_size,
                              hipStream_t stream) {
    const float* E      = (const float*)d_in[0];
    const float* gamma  = (const float*)d_in[1];
    const float* beta   = (const float*)d_in[2];
    const float* W_gnn  = (const float*)d_in[3];
    const float* b_gnn  = (const float*)d_in[4];
    const float* W_g    = (const float*)d_in[5];
    const float* b_g    = (const float*)d_in[6];
    const float* W_age  = (const float*)d_in[7];
    const float* b_age  = (const float*)d_in[8];
    const float* W_occ  = (const float*)d_in[9];
    const float* b_occ  = (const float*)d_in[10];
    const int*   src    = (const int*)d_in[11];
    const int*   dst    = (const int*)d_in[12];
    const int*   neigh  = (const int*)d_in[13];
    const int*   gender = (const int*)d_in[14];

    float*          ws      = (float*)d_ws;
    int*            wsi     = (int*)d_ws;
    float*          scale   = ws + WS_SCALE;
    float*          shift   = ws + WS_SHIFT;
    int*            count   = wsi + WS_COUNT;
    int*            bcount  = wsi + WS_BCOUNT;
    int*            slot_of = wsi + WS_SLOTOF;
    int*            bucket  = wsi + WS_BUCKET;
    float*          slot_hd = ws + WS_SLOTHEAD;
    float*          partial = ws + WS_PARTIAL;
    unsigned short* Ebf     = (unsigned short*)(ws + WS_EBF);

    float* out       = (float*)d_out;
    float* out_loss  = out;                         // [1]
    float* out_age   = out + 1;                     // [8192,7]
    float* out_gen   = out + 1 + BATCH * 7;         // [8192]
    float* out_occ   = out + 1 + BATCH * 7 + BATCH; // [8192,21]

    init_kernel<<<(N_ENT + 255) / 256, 256, 0, stream>>>(slot_of, bcount, count, out_loss);
    mark_kernel<<<BATCH / 256, 256, 0, stream>>>(neigh, slot_of);
    compact_kernel<<<(N_ENT + 255) / 256, 256, 0, stream>>>(slot_of, count);
    {
        const int n4 = N_EDGES / 4;
        int nthreads = (n4 + 1) / 2;
        edge_bucket_kernel<<<(nthreads + 255) / 256, 256, 0, stream>>>(
            (const int4*)src, (const int4*)dst, slot_of, bcount, bucket);
    }
    // stats (+ bf16 copy) directly before gather: Ebf stays L2/LLC-warm
    stats_kernel<<<NSTAT_BLK, 256, 0, stream>>>((const float4*)E, Ebf, partial);
    finalize_kernel<<<1, 256, 0, stream>>>(partial, gamma, beta, scale, shift);
    gather_gemm_heads_kernel<<<BATCH / 4, 256, 0, stream>>>(
        Ebf, count, bcount, bucket,
        (const float4*)scale, (const float4*)shift,
        (const float4*)W_gnn, (const float4*)b_gnn,
        W_g, b_g, W_age, b_age, W_occ, b_occ, slot_hd);
    map_loss_kernel<<<BATCH / 256, 256, 0, stream>>>(slot_hd, slot_of, neigh, gender,
                                                     out_age, out_gen, out_occ, out_loss);
}

// Round 9
// 209.636 us; speedup vs baseline: 1.0227x; 1.0184x over previous
//
#include <hip/hip_runtime.h>
#include <hip/hip_bf16.h>
#include <math.h>

#define N_ENT   100000
#define DIM     128
#define N_EDGES 1600000
#define BATCH   8192
#define EPS     1e-5f
#define CAP     128          // max neighbors stored per needed node (Poisson(16) tail ~0)
#define NSTAT_BLK   512
#define NGATHER_BLK (BATCH / 4)   // 2048

// ---------------- ws layout (4-byte elements) ----------------
#define WS_SCALE     256        // f[128]
#define WS_SHIFT     384        // f[128]
#define WS_COUNT     512        // i[16] (count in [0])
#define WS_BCOUNT    528        // i[8192] per-slot edge count (== degree)
#define WS_SLOTOF    8720       // i[100000]  (-1 = unneeded, -2 = marked, >=0 = slot)
#define WS_BUCKET    108720     // i[8192*128]   (16B aligned)
#define WS_SLOTHEAD  1157296    // f[8192*32]    per-slot head logits (age 0-6, occ 7-27, gender 28)
#define WS_PARTIAL   1419440    // f[512*256]    stats partials
#define WS_HSUM      1550512    // f[8192*128]   raw per-slot sums (4 MB), 16B aligned

// K0: init slot_of/-counters (ws poisoned 0xAA before every launch; slot_of
// init kept as insurance even though poison is a negative int).
__global__ __launch_bounds__(256) void init_kernel(int* __restrict__ slot_of,
                                                   int* __restrict__ bcount,
                                                   int* __restrict__ count,
                                                   float* __restrict__ out_loss) {
    int n = blockIdx.x * 256 + threadIdx.x;
    if (n < N_ENT) slot_of[n] = -1;
    if (n < BATCH) bcount[n] = 0;
    if (n < 16)    count[n] = 0;
    if (n == 0)    out_loss[0] = 0.f;
}

// K1: mark needed nodes (idempotent stores).
__global__ __launch_bounds__(256) void mark_kernel(const int* __restrict__ neighbor,
                                                   int* __restrict__ slot_of) {
    int b = blockIdx.x * 256 + threadIdx.x;
    if (b < BATCH) slot_of[neighbor[b]] = -2;
}

// K2: assign compact slots to marked nodes — 1 global atomic per block.
__global__ __launch_bounds__(256) void compact_kernel(int* __restrict__ slot_of,
                                                      int* __restrict__ count) {
    int n = blockIdx.x * 256 + threadIdx.x;
    bool marked = (n < N_ENT && slot_of[n] == -2);
    unsigned long long m = __ballot(marked);
    int lane = threadIdx.x & 63;
    int wid = threadIdx.x >> 6;
    int prefix = __popcll(m & ((1ull << lane) - 1ull));
    __shared__ int wsum[4];
    __shared__ int base;
    if (lane == 0) wsum[wid] = __popcll(m);
    __syncthreads();
    if (threadIdx.x == 0) {
        base = atomicAdd(count, wsum[0] + wsum[1] + wsum[2] + wsum[3]);
    }
    __syncthreads();
    int wbase = 0;
    for (int i = 0; i < wid; ++i) wbase += wsum[i];
    if (marked) slot_of[n] = base + wbase + prefix;
}

// K3: single-pass edge bucket — 8 edges/thread, 8 independent slot_of probes.
__global__ __launch_bounds__(256) void edge_bucket_kernel(const int4* __restrict__ src4,
                                                          const int4* __restrict__ dst4,
                                                          const int* __restrict__ slot_of,
                                                          int* __restrict__ bcount,
                                                          int* __restrict__ bucket) {
    const int n4 = N_EDGES / 4;   // 400000, exact
    int tid = blockIdx.x * blockDim.x + threadIdx.x;
    int e0 = tid * 2;
    int e1 = tid * 2 + 1;
    if (e0 >= n4) return;
    int4 d0 = dst4[e0];
    int4 s0 = src4[e0];
    bool has1 = (e1 < n4);
    int4 d1 = has1 ? dst4[e1] : make_int4(0, 0, 0, 0);
    int4 s1 = has1 ? src4[e1] : make_int4(0, 0, 0, 0);
    int sl0 = slot_of[d0.x];
    int sl1 = slot_of[d0.y];
    int sl2 = slot_of[d0.z];
    int sl3 = slot_of[d0.w];
    int sl4 = has1 ? slot_of[d1.x] : -1;
    int sl5 = has1 ? slot_of[d1.y] : -1;
    int sl6 = has1 ? slot_of[d1.z] : -1;
    int sl7 = has1 ? slot_of[d1.w] : -1;
    if (sl0 >= 0) { int p = atomicAdd(&bcount[sl0], 1); if (p < CAP) bucket[sl0 * CAP + p] = s0.x; }
    if (sl1 >= 0) { int p = atomicAdd(&bcount[sl1], 1); if (p < CAP) bucket[sl1 * CAP + p] = s0.y; }
    if (sl2 >= 0) { int p = atomicAdd(&bcount[sl2], 1); if (p < CAP) bucket[sl2 * CAP + p] = s0.z; }
    if (sl3 >= 0) { int p = atomicAdd(&bcount[sl3], 1); if (p < CAP) bucket[sl3 * CAP + p] = s0.w; }
    if (sl4 >= 0) { int p = atomicAdd(&bcount[sl4], 1); if (p < CAP) bucket[sl4 * CAP + p] = s1.x; }
    if (sl5 >= 0) { int p = atomicAdd(&bcount[sl5], 1); if (p < CAP) bucket[sl5 * CAP + p] = s1.y; }
    if (sl6 >= 0) { int p = atomicAdd(&bcount[sl6], 1); if (p < CAP) bucket[sl6 * CAP + p] = s1.z; }
    if (sl7 >= 0) { int p = atomicAdd(&bcount[sl7], 1); if (p < CAP) bucket[sl7 * CAP + p] = s1.w; }
}

// K4: FUSED stats || gather — independent stages in one launch so the
// streaming stats hides under the latency-bound gather (single stream
// serializes separate launches). Gather blocks first (long pole starts first).
//  - blocks [0, NGATHER_BLK): per-slot raw fp32 sums of E[src] -> hsum
//    (normalization deferred to the GEMM; no dependency on stats here)
//  - blocks [NGATHER_BLK, +NSTAT_BLK): column sum/sumsq partials of E
__global__ __launch_bounds__(256) void stats_gather_kernel(const float4* __restrict__ E4,
                                                           const int* __restrict__ count,
                                                           const int* __restrict__ bcount,
                                                           const int* __restrict__ bucket,
                                                           float* __restrict__ hsum,
                                                           float* __restrict__ partial) {
    int t = threadIdx.x;
    if (blockIdx.x < NGATHER_BLK) {
        // ---- gather body (no LDS, no __syncthreads) ----
        int slot = blockIdx.x * 4 + (t >> 6);
        int U = count[0];
        if (slot >= U) return;
        int lane = t & 63;
        int q = lane & 31;
        int sub = lane >> 5;
        int dg = bcount[slot];
        int m = dg < CAP ? dg : CAP;
        const int* bk = bucket + slot * CAP;
        float ax = 0.f, ay = 0.f, az = 0.f, aw = 0.f;
        int i = sub;
        for (; i + 6 < m; i += 8) {
            int r0 = bk[i], r1 = bk[i + 2], r2 = bk[i + 4], r3 = bk[i + 6];
            float4 v0 = E4[(size_t)r0 * 32 + q];
            float4 v1 = E4[(size_t)r1 * 32 + q];
            float4 v2 = E4[(size_t)r2 * 32 + q];
            float4 v3 = E4[(size_t)r3 * 32 + q];
            ax += v0.x + v1.x + v2.x + v3.x;
            ay += v0.y + v1.y + v2.y + v3.y;
            az += v0.z + v1.z + v2.z + v3.z;
            aw += v0.w + v1.w + v2.w + v3.w;
        }
        for (; i < m; i += 2) {
            int r0 = bk[i];
            float4 v0 = E4[(size_t)r0 * 32 + q];
            ax += v0.x; ay += v0.y; az += v0.z; aw += v0.w;
        }
        ax += __shfl_down(ax, 32);
        ay += __shfl_down(ay, 32);
        az += __shfl_down(az, 32);
        aw += __shfl_down(aw, 32);
        if (sub == 0) {
            float4 o; o.x = ax; o.y = ay; o.z = az; o.w = aw;
            ((float4*)(hsum + (size_t)slot * DIM))[q] = o;
        }
        return;
    }
    // ---- stats body ----
    int sid = blockIdx.x - NGATHER_BLK;
    int cg = t & 31;
    int rs = t >> 5;
    const int STRIDE = NSTAT_BLK * 8;   // 4096 rows per sweep
    float sx = 0.f, sy = 0.f, sz = 0.f, sw = 0.f;
    float qx = 0.f, qy = 0.f, qz = 0.f, qw = 0.f;
    const float4 z4 = make_float4(0.f, 0.f, 0.f, 0.f);
    for (int r = sid * 8 + rs; r < N_ENT; r += 4 * STRIDE) {
        int r1 = r + STRIDE, r2 = r + 2 * STRIDE, r3 = r + 3 * STRIDE;
        float4 v0 = E4[(size_t)r * 32 + cg];
        float4 v1 = (r1 < N_ENT) ? E4[(size_t)r1 * 32 + cg] : z4;
        float4 v2 = (r2 < N_ENT) ? E4[(size_t)r2 * 32 + cg] : z4;
        float4 v3 = (r3 < N_ENT) ? E4[(size_t)r3 * 32 + cg] : z4;
        sx += v0.x + v1.x + v2.x + v3.x;
        sy += v0.y + v1.y + v2.y + v3.y;
        sz += v0.z + v1.z + v2.z + v3.z;
        sw += v0.w + v1.w + v2.w + v3.w;
        qx += v0.x * v0.x + v1.x * v1.x + v2.x * v2.x + v3.x * v3.x;
        qy += v0.y * v0.y + v1.y * v1.y + v2.y * v2.y + v3.y * v3.y;
        qz += v0.z * v0.z + v1.z * v1.z + v2.z * v2.z + v3.z * v3.z;
        qw += v0.w * v0.w + v1.w * v1.w + v2.w * v2.w + v3.w * v3.w;
    }
    __shared__ float sh[8 * 256];
    sh[0 * 256 + t] = sx; sh[1 * 256 + t] = sy;
    sh[2 * 256 + t] = sz; sh[3 * 256 + t] = sw;
    sh[4 * 256 + t] = qx; sh[5 * 256 + t] = qy;
    sh[6 * 256 + t] = qz; sh[7 * 256 + t] = qw;
    __syncthreads();
    for (int o = 128; o >= 32; o >>= 1) {
        if (t < o) {
#pragma unroll
            for (int j = 0; j < 8; ++j) sh[j * 256 + t] += sh[j * 256 + t + o];
        }
        __syncthreads();
    }
    if (t < 32) {
#pragma unroll
        for (int j = 0; j < 8; ++j)
            partial[sid * 256 + j * 32 + t] = sh[j * 256 + t];
    }
}

// K5: reduce partials; fold batchnorm into per-column scale/shift.
__global__ __launch_bounds__(256) void finalize_kernel(const float* __restrict__ partial,
                                                       const float* __restrict__ gamma,
                                                       const float* __restrict__ beta,
                                                       float* __restrict__ scale,
                                                       float* __restrict__ shift) {
    int t = threadIdx.x;
    float s = 0.f;
    for (int b = 0; b < NSTAT_BLK; ++b) s += partial[b * 256 + t];
    __shared__ float tot[256];
    tot[t] = s;
    __syncthreads();
    if (t < 128) {
        int ti = t >> 2, j = t & 3;
        const float invn = 1.0f / (float)N_ENT;
        float mu = tot[j * 32 + ti] * invn;
        float var = tot[(j + 4) * 32 + ti] * invn - mu * mu;
        float rs = rsqrtf(var + EPS);
        float sc = gamma[t] * rs;
        scale[t] = sc;
        shift[t] = beta[t] - mu * sc;
    }
}

#define HW_LD 132   // padded leading dim for head-weight LDS tile (bank spread)

// K6: tiled norm+GEMM+heads. 32 slots/block, thread owns 4x4 of h2.
//  A-staging applies h = (S*scale + deg*shift)/max(deg,1) on the fly;
//  h2 = relu(A @ W + b) is written back to LDS; then 32x29 head logits
//  computed from the LDS tile with LDS-staged head weights.
__global__ __launch_bounds__(256) void gemm_heads_kernel(const float* __restrict__ hsum,
                                                         const int* __restrict__ bcount,
                                                         const float* __restrict__ scale,
                                                         const float* __restrict__ shift,
                                                         const float4* __restrict__ W4,
                                                         const float4* __restrict__ bias4,
                                                         const float* __restrict__ W_g,
                                                         const float* __restrict__ b_g,
                                                         const float* __restrict__ W_age,
                                                         const float* __restrict__ b_age,
                                                         const float* __restrict__ W_occ,
                                                         const float* __restrict__ b_occ,
                                                         float* __restrict__ slot_heads) {
    __shared__ float A_s[32 * 128];       // 16 KB: h tile, then h2 tile
    __shared__ float HW[29 * HW_LD];      // 15.3 KB: head weights [h][d]
    __shared__ float hb[32];
    int t = threadIdx.x;
    int rowbase = blockIdx.x * 32;

    // stage A with affine: 1024 float4 / 256 threads
    const float4* S4 = (const float4*)(hsum + (size_t)rowbase * DIM);
    const float4* sc4 = (const float4*)scale;
    const float4* sf4 = (const float4*)shift;
#pragma unroll
    for (int i = 0; i < 4; ++i) {
        int f4 = t + i * 256;
        int row = f4 >> 5;
        int cgl = f4 & 31;
        float fdg = (float)bcount[rowbase + row];
        float rd = 1.0f / fmaxf(fdg, 1.0f);
        float4 v = S4[f4];
        float4 sc = sc4[cgl];
        float4 sf = sf4[cgl];
        float4 o;
        o.x = (v.x * sc.x + fdg * sf.x) * rd;
        o.y = (v.y * sc.y + fdg * sf.y) * rd;
        o.z = (v.z * sc.z + fdg * sf.z) * rd;
        o.w = (v.w * sc.w + fdg * sf.w) * rd;
        ((float4*)A_s)[f4] = o;
    }
    // stage head weights: HW[h][d] = head h's weight for dim d
    for (int idx = t; idx < 29 * 128; idx += 256) {
        int h = idx >> 7;
        int d = idx & 127;
        float v;
        if (h < 7)       v = W_age[d * 7 + h];
        else if (h < 28) v = W_occ[d * 21 + (h - 7)];
        else             v = W_g[d];
        HW[h * HW_LD + d] = v;
    }
    if (t < 29) hb[t] = (t < 7) ? b_age[t] : (t < 28) ? b_occ[t - 7] : b_g[0];
    __syncthreads();

    // GEMM: thread owns rows [rg*4, +4) x cols [cg*4, +4)
    int cg = t & 31;
    int rg = t >> 5;
    int r0 = rg * 4;
    float acc[4][4] = {{0.f}};
#pragma unroll 4
    for (int k = 0; k < 128; ++k) {
        float4 wv = W4[k * 32 + cg];
#pragma unroll
        for (int i = 0; i < 4; ++i) {
            float a = A_s[(r0 + i) * 128 + k];
            acc[i][0] += a * wv.x;
            acc[i][1] += a * wv.y;
            acc[i][2] += a * wv.z;
            acc[i][3] += a * wv.w;
        }
    }
    float4 bv = bias4[cg];
    __syncthreads();   // all A_s reads done before overwrite
#pragma unroll
    for (int i = 0; i < 4; ++i) {
        float4 o;
        o.x = fmaxf(acc[i][0] + bv.x, 0.f);
        o.y = fmaxf(acc[i][1] + bv.y, 0.f);
        o.z = fmaxf(acc[i][2] + bv.z, 0.f);
        o.w = fmaxf(acc[i][3] + bv.w, 0.f);
        ((float4*)A_s)[(r0 + i) * 32 + cg] = o;
    }
    __syncthreads();

    // heads: 32 rows x 32 head-slots (h<29 live) = 1024 tasks, 4 per thread
#pragma unroll
    for (int i = 0; i < 4; ++i) {
        int task = t + i * 256;
        int row = task >> 5;
        int h = task & 31;
        if (h < 29) {
            const float4* h4 = (const float4*)(A_s + row * 128);
            const float4* w4 = (const float4*)(HW + h * HW_LD);
            float a0 = hb[h], a1 = 0.f, a2 = 0.f, a3 = 0.f;
#pragma unroll 8
            for (int dd = 0; dd < 32; ++dd) {
                float4 hv = h4[dd];
                float4 wv = w4[dd];
                a0 += hv.x * wv.x;
                a1 += hv.y * wv.y;
                a2 += hv.z * wv.z;
                a3 += hv.w * wv.w;
            }
            slot_heads[(size_t)(rowbase + row) * 32 + h] = a0 + a1 + a2 + a3;
        }
    }
}

// K7: map per-slot head logits to batch outputs + fused BCE loss.
__global__ __launch_bounds__(256) void map_loss_kernel(const float* __restrict__ slot_heads,
                                                       const int* __restrict__ slot_of,
                                                       const int* __restrict__ neighbor,
                                                       const int* __restrict__ gender,
                                                       float* __restrict__ out_age,
                                                       float* __restrict__ out_gender,
                                                       float* __restrict__ out_occ,
                                                       float* __restrict__ out_loss) {
    int b = blockIdx.x * 256 + threadIdx.x;
    float val = 0.f;
    if (b < BATCH) {
        int slot = slot_of[neighbor[b]];
        const float* hs = slot_heads + (size_t)slot * 32;
#pragma unroll
        for (int c = 0; c < 7; ++c)  out_age[b * 7 + c] = hs[c];
#pragma unroll
        for (int c = 0; c < 21; ++c) out_occ[b * 21 + c] = hs[7 + c];
        float x = hs[28];
        out_gender[b] = x;
        float z = (float)gender[b];
        val = fmaxf(x, 0.f) - x * z + log1pf(expf(-fabsf(x)));
    }
    __shared__ float sh[256];
    sh[threadIdx.x] = val;
    __syncthreads();
    for (int o = 128; o > 0; o >>= 1) {
        if (threadIdx.x < o) sh[threadIdx.x] += sh[threadIdx.x + o];
        __syncthreads();
    }
    if (threadIdx.x == 0) atomicAdd(out_loss, sh[0] * (1.0f / (float)BATCH));
}

extern "C" void kernel_launch(void* const* d_in, const int* in_sizes, int n_in,
                              void* d_out, int out_size, void* d_ws, size_t ws_size,
                              hipStream_t stream) {
    const float* E      = (const float*)d_in[0];
    const float* gamma  = (const float*)d_in[1];
    const float* beta   = (const float*)d_in[2];
    const float* W_gnn  = (const float*)d_in[3];
    const float* b_gnn  = (const float*)d_in[4];
    const float* W_g    = (const float*)d_in[5];
    const float* b_g    = (const float*)d_in[6];
    const float* W_age  = (const float*)d_in[7];
    const float* b_age  = (const float*)d_in[8];
    const float* W_occ  = (const float*)d_in[9];
    const float* b_occ  = (const float*)d_in[10];
    const int*   src    = (const int*)d_in[11];
    const int*   dst    = (const int*)d_in[12];
    const int*   neigh  = (const int*)d_in[13];
    const int*   gender = (const int*)d_in[14];

    float* ws      = (float*)d_ws;
    int*   wsi     = (int*)d_ws;
    float* scale   = ws + WS_SCALE;
    float* shift   = ws + WS_SHIFT;
    int*   count   = wsi + WS_COUNT;
    int*   bcount  = wsi + WS_BCOUNT;
    int*   slot_of = wsi + WS_SLOTOF;
    int*   bucket  = wsi + WS_BUCKET;
    float* slot_hd = ws + WS_SLOTHEAD;
    float* partial = ws + WS_PARTIAL;
    float* hsum    = ws + WS_HSUM;

    float* out       = (float*)d_out;
    float* out_loss  = out;                         // [1]
    float* out_age   = out + 1;                     // [8192,7]
    float* out_gen   = out + 1 + BATCH * 7;         // [8192]
    float* out_occ   = out + 1 + BATCH * 7 + BATCH; // [8192,21]

    init_kernel<<<(N_ENT + 255) / 256, 256, 0, stream>>>(slot_of, bcount, count, out_loss);
    mark_kernel<<<BATCH / 256, 256, 0, stream>>>(neigh, slot_of);
    compact_kernel<<<(N_ENT + 255) / 256, 256, 0, stream>>>(slot_of, count);
    {
        const int n4 = N_EDGES / 4;
        int nthreads = (n4 + 1) / 2;
        edge_bucket_kernel<<<(nthreads + 255) / 256, 256, 0, stream>>>(
            (const int4*)src, (const int4*)dst, slot_of, bcount, bucket);
    }
    stats_gather_kernel<<<NGATHER_BLK + NSTAT_BLK, 256, 0, stream>>>(
        (const float4*)E, count, bcount, bucket, hsum, partial);
    finalize_kernel<<<1, 256, 0, stream>>>(partial, gamma, beta, scale, shift);
    gemm_heads_kernel<<<BATCH / 32, 256, 0, stream>>>(
        hsum, bcount, scale, shift,
        (const float4*)W_gnn, (const float4*)b_gnn,
        W_g, b_g, W_age, b_age, W_occ, b_occ, slot_hd);
    map_loss_kernel<<<BATCH / 256, 256, 0, stream>>>(slot_hd, slot_of, neigh, gender,
                                                     out_age, out_gen, out_occ, out_loss);
}